// Round 8
// baseline (362.095 us; speedup 1.0000x reference)
//
#include <hip/hip_runtime.h>
#include <math.h>

typedef _Float16 half_t;
typedef __attribute__((ext_vector_type(4))) _Float16 half4v;
typedef __attribute__((ext_vector_type(8))) _Float16 half8v;
typedef __attribute__((ext_vector_type(4))) float floatx4;

constexpr int B_ = 4, S_ = 4096, D_ = 2048, H_ = 1024, H2_ = 512, E_ = 8;
constexpr int CHUNK_ = 128;
constexpr int C_ = S_ / CHUNK_;          // 32
constexpr int M_ = B_ * S_;              // 16384
constexpr float TAU_ = 0.7f;
// Precision ledger (measured): x/W1 pure-f16 + W2 split -> absmax = 2^-9
// (R4-R7), 60x under threshold. W2 residual kept: h1>=0 makes W2-rounding
// coherent through the chunk mean; x/W1 rounding is token-incoherent.
constexpr float WSCALE = 64.0f, OSCALE = 1.0f / 64.0f;

constexpr int OUT_RW = 0;
constexpr int OUT_EI = OUT_RW + B_ * S_ * E_;
constexpr int OUT_CL = OUT_EI + B_ * C_;
constexpr int OUT_GE = OUT_CL + B_ * C_ * E_;
constexpr int OUT_UT = OUT_GE + 1;
constexpr int OUT_FR = OUT_UT + E_;
constexpr int OUT_RC = OUT_FR + 1;

// ---------------------------------------------------------------------------
// Prep (one launch): x->f16 | w1 transpose | w2 transpose+split | cl_acc zero
// ---------------------------------------------------------------------------
__global__ __launch_bounds__(256)
void prep_kernel(const float* __restrict__ x, const float* __restrict__ w1,
                 const float* __restrict__ w2,
                 half_t* __restrict__ xh, half_t* __restrict__ w1t,
                 half_t* __restrict__ w2th, half_t* __restrict__ w2tl,
                 float* __restrict__ cl_acc)
{
    __shared__ float tile[32][33];
    const int tx = threadIdx.x & 31;
    const int ty = threadIdx.x >> 5;
    const int bid = blockIdx.x;

    if (bid < 8192) {                     // convert x: 1024 float4 per block
        const int base = bid * 1024 + threadIdx.x;
#pragma unroll
        for (int p = 0; p < 4; ++p) {
            const int i = base + p * 256;
            const float4 v = ((const float4*)x)[i];
            half4v h;
            h.x = (half_t)v.x; h.y = (half_t)v.y; h.z = (half_t)v.z; h.w = (half_t)v.w;
            ((half4v*)xh)[i] = h;
        }
    } else if (bid < 10240) {             // w1 transpose -> f16
        const int b2 = bid - 8192;
        const int n0 = (b2 & 31) * 32;
        const int k0 = (b2 >> 5) * 32;
#pragma unroll
        for (int r = 0; r < 4; ++r)
            tile[ty + r * 8][tx] = w1[(size_t)(k0 + ty + r * 8) * H_ + n0 + tx];
        __syncthreads();
#pragma unroll
        for (int r = 0; r < 4; ++r)
            w1t[(size_t)(n0 + ty + r * 8) * D_ + k0 + tx] = (half_t)tile[tx][ty + r * 8];
    } else if (bid < 10752) {             // w2 transpose + split
        const int b2 = bid - 10240;
        const int n0 = (b2 & 15) * 32;
        const int k0 = (b2 >> 4) * 32;
#pragma unroll
        for (int r = 0; r < 4; ++r)
            tile[ty + r * 8][tx] = w2[(size_t)(k0 + ty + r * 8) * H2_ + n0 + tx];
        __syncthreads();
#pragma unroll
        for (int r = 0; r < 4; ++r) {
            const float v = tile[tx][ty + r * 8] * WSCALE;
            const half_t h = (half_t)v;
            const size_t off = (size_t)(n0 + ty + r * 8) * H_ + k0 + tx;
            w2th[off] = h;
            w2tl[off] = (half_t)(v - (float)h);
        }
    } else {
        for (int i = threadIdx.x; i < B_ * C_ * E_; i += 256) cl_acc[i] = 0.0f;
    }
}

// ---------------------------------------------------------------------------
// GEMM1: h1 = relu(xh @ w1 + b1) -> f16. Pure f16 MFMA, 128x128 tile, BK=64
// (half the barrier drains vs BK=32), dual global_load_lds(16B), 32 KB LDS.
// ---------------------------------------------------------------------------
__global__ __launch_bounds__(256, 4)
void gemm1_kernel(const half_t* __restrict__ Ah,
                  const half_t* __restrict__ BTh,
                  const float* __restrict__ bias, half_t* __restrict__ outh)
{
    constexpr int KD = D_, ND = H_, BK = 64;
    __shared__ __align__(16) half_t sA[128 * BK];   // 16 KB
    __shared__ __align__(16) half_t sB[128 * BK];   // 16 KB

    const int tid = threadIdx.x;
    const int lane = tid & 63;
    const int wave = tid >> 6;
    const int wm = (wave & 1) * 64;
    const int wn = (wave >> 1) * 64;
    const int rowBlk = blockIdx.x * 16 + (blockIdx.y >> 3);
    const int colBlk = blockIdx.y & 7;
    const long blockM = (long)rowBlk * 128;
    const long blockN = (long)colBlk * 128;

    floatx4 acc[4][4];
#pragma unroll
    for (int i = 0; i < 4; ++i)
#pragma unroll
        for (int j = 0; j < 4; ++j) acc[i][j] = (floatx4){0.f, 0.f, 0.f, 0.f};

    // staging: 128 rows x 64 f16 = 16 KB per stream -> 4 passes of 16 B/thread
    const int srow = tid >> 3;            // 0..31
    const int skoff = (tid & 7) * 8;      // 0..56
    const int ldsoff = srow * BK + skoff;
    const int fr = lane & 15;
    const int fq = (lane >> 4) * 8;

    for (int k0 = 0; k0 < KD; k0 += BK) {
        __syncthreads();
#pragma unroll
        for (int p = 0; p < 4; ++p) {
            const int row = srow + p * 32;
            const size_t aoff = (size_t)(blockM + row) * KD + k0 + skoff;
            const size_t boff = (size_t)(blockN + row) * KD + k0 + skoff;
            const int loff = ldsoff + p * 32 * BK;
            __builtin_amdgcn_global_load_lds(
                (const __attribute__((address_space(1))) void*)(Ah + aoff),
                (__attribute__((address_space(3))) void*)(sA + loff), 16, 0, 0);
            __builtin_amdgcn_global_load_lds(
                (const __attribute__((address_space(1))) void*)(BTh + boff),
                (__attribute__((address_space(3))) void*)(sB + loff), 16, 0, 0);
        }
        __syncthreads();

#pragma unroll
        for (int kt = 0; kt < 2; ++kt) {
            half8v fb[4];
#pragma unroll
            for (int t = 0; t < 4; ++t)
                fb[t] = *(const half8v*)(sB + (wn + t * 16 + fr) * BK + kt * 32 + fq);
#pragma unroll
            for (int i = 0; i < 4; ++i) {
                const half8v fa = *(const half8v*)(sA + (wm + i * 16 + fr) * BK + kt * 32 + fq);
#pragma unroll
                for (int j = 0; j < 4; ++j)
                    acc[i][j] = __builtin_amdgcn_mfma_f32_16x16x32_f16(fa, fb[j], acc[i][j], 0, 0, 0);
            }
        }
    }

    const int orow = (lane >> 4) * 4;
    const int ocol = lane & 15;
#pragma unroll
    for (int j = 0; j < 4; ++j) {
        const long gn = blockN + wn + j * 16 + ocol;
        const float bj = bias[gn];
#pragma unroll
        for (int i = 0; i < 4; ++i) {
#pragma unroll
            for (int r = 0; r < 4; ++r) {
                const float v = fmaxf(acc[i][j][r] + bj, 0.0f);
                const size_t off = (size_t)(blockM + wm + i * 16 + orow + r) * ND + gn;
                outh[off] = (half_t)v;
            }
        }
    }
}

// ---------------------------------------------------------------------------
// GEMM2 fused: relu(h1 @ w2 + b2) @ w3, chunk-summed into cl_acc.
// 128x64 tile (1024 blocks = 4/CU for wave-overlap), BK=64, f16x2 W2-split,
// 32 KB LDS. h2 never materialized.
// ---------------------------------------------------------------------------
__global__ __launch_bounds__(256, 4)
void gemm2_fused_kernel(const half_t* __restrict__ Ah,
                        const half_t* __restrict__ BTh, const half_t* __restrict__ BTl,
                        const float* __restrict__ bias, const float* __restrict__ w3,
                        float* __restrict__ cl_acc)
{
    constexpr int KD = H_, BK = 64;
    __shared__ __align__(16) half_t sAh[128 * BK];  // 16 KB
    __shared__ __align__(16) half_t sBh[64 * BK];   // 8 KB
    __shared__ __align__(16) half_t sBl[64 * BK];   // 8 KB

    const int tid = threadIdx.x;
    const int lane = tid & 63;
    const int wave = tid >> 6;
    const int wm = (wave & 1) * 64;       // 2 wave-rows
    const int wn = (wave >> 1) * 32;      // 2 wave-cols of 32
    const int rowBlk = blockIdx.x * 16 + (blockIdx.y >> 3);   // chunk id 0..127
    const int colBlk = blockIdx.y & 7;    // 8 x 64 = N=512
    const long blockM = (long)rowBlk * 128;
    const long blockN = (long)colBlk * 64;

    floatx4 acc[4][2];
#pragma unroll
    for (int i = 0; i < 4; ++i)
#pragma unroll
        for (int j = 0; j < 2; ++j) acc[i][j] = (floatx4){0.f, 0.f, 0.f, 0.f};

    const int srow = tid >> 3;            // 0..31
    const int skoff = (tid & 7) * 8;
    const int ldsoff = srow * BK + skoff;
    const int fr = lane & 15;
    const int fq = (lane >> 4) * 8;

    for (int k0 = 0; k0 < KD; k0 += BK) {
        __syncthreads();
        // A: 128 rows -> 4 passes
#pragma unroll
        for (int p = 0; p < 4; ++p) {
            const int row = srow + p * 32;
            const size_t aoff = (size_t)(blockM + row) * KD + k0 + skoff;
            __builtin_amdgcn_global_load_lds(
                (const __attribute__((address_space(1))) void*)(Ah + aoff),
                (__attribute__((address_space(3))) void*)(sAh + ldsoff + p * 32 * BK), 16, 0, 0);
        }
        // B hi/lo: 64 rows -> 2 passes each
#pragma unroll
        for (int p = 0; p < 2; ++p) {
            const int row = srow + p * 32;
            const size_t boff = (size_t)(blockN + row) * KD + k0 + skoff;
            const int loff = ldsoff + p * 32 * BK;
            __builtin_amdgcn_global_load_lds(
                (const __attribute__((address_space(1))) void*)(BTh + boff),
                (__attribute__((address_space(3))) void*)(sBh + loff), 16, 0, 0);
            __builtin_amdgcn_global_load_lds(
                (const __attribute__((address_space(1))) void*)(BTl + boff),
                (__attribute__((address_space(3))) void*)(sBl + loff), 16, 0, 0);
        }
        __syncthreads();

#pragma unroll
        for (int kt = 0; kt < 2; ++kt) {
            half8v fbh[2], fbl[2];
#pragma unroll
            for (int t = 0; t < 2; ++t) {
                fbh[t] = *(const half8v*)(sBh + (wn + t * 16 + fr) * BK + kt * 32 + fq);
                fbl[t] = *(const half8v*)(sBl + (wn + t * 16 + fr) * BK + kt * 32 + fq);
            }
#pragma unroll
            for (int i = 0; i < 4; ++i) {
                const half8v fah = *(const half8v*)(sAh + (wm + i * 16 + fr) * BK + kt * 32 + fq);
#pragma unroll
                for (int j = 0; j < 2; ++j) {
                    acc[i][j] = __builtin_amdgcn_mfma_f32_16x16x32_f16(fah, fbh[j], acc[i][j], 0, 0, 0);
                    acc[i][j] = __builtin_amdgcn_mfma_f32_16x16x32_f16(fah, fbl[j], acc[i][j], 0, 0, 0);
                }
            }
        }
    }

    // Epilogue: relu(h2) -> dot w3 rows -> wave reduce -> atomicAdd per chunk.
    const int ocol = lane & 15;
    float p[E_];
#pragma unroll
    for (int e = 0; e < E_; ++e) p[e] = 0.0f;
#pragma unroll
    for (int j = 0; j < 2; ++j) {
        const int gn = (int)blockN + wn + j * 16 + ocol;   // h2 column in [0,512)
        const float bj = bias[gn];
        const float4 w3a = *(const float4*)(w3 + (size_t)gn * E_);
        const float4 w3b = *(const float4*)(w3 + (size_t)gn * E_ + 4);
        float colsum = 0.0f;
#pragma unroll
        for (int i = 0; i < 4; ++i)
#pragma unroll
            for (int r = 0; r < 4; ++r)
                colsum += fmaxf(acc[i][j][r] * OSCALE + bj, 0.0f);
        p[0] += colsum * w3a.x; p[1] += colsum * w3a.y;
        p[2] += colsum * w3a.z; p[3] += colsum * w3a.w;
        p[4] += colsum * w3b.x; p[5] += colsum * w3b.y;
        p[6] += colsum * w3b.z; p[7] += colsum * w3b.w;
    }
#pragma unroll
    for (int e = 0; e < E_; ++e)
#pragma unroll
        for (int off = 32; off > 0; off >>= 1)
            p[e] += __shfl_xor(p[e], off);
#pragma unroll
    for (int e = 0; e < E_; ++e)
        if (lane == e) atomicAdd(&cl_acc[rowBlk * E_ + e], p[e]);
}

// ---------------------------------------------------------------------------
// Final+route: all 64 blocks redundantly compute logits+argmax+scan (4 KB),
// write their routing-weight slice; block 0 writes EI/CL/stats.
// prev_expert_indices is dead in the reference (scan init zeros + is_first).
// ---------------------------------------------------------------------------
__global__ __launch_bounds__(256)
void final_route_kernel(const float* __restrict__ cl_acc, const float* __restrict__ b3,
                        float* __restrict__ out)
{
    __shared__ float cl[B_ * C_][E_];
    __shared__ int tops[B_ * C_];
    __shared__ int finals[B_ * C_];
    __shared__ int flips[B_];
    __shared__ float ent[B_ * C_];

    const int tid = threadIdx.x;

    if (tid < B_ * C_) {
        int best = 0;
        float bvv = -1e30f;
#pragma unroll
        for (int e = 0; e < E_; ++e) {
            const float v = cl_acc[tid * E_ + e] * (1.0f / CHUNK_) + b3[e];
            cl[tid][e] = v;
            if (v > bvv) { bvv = v; best = e; }   // first-max tiebreak == np.argmax
        }
        tops[tid] = best;
    }
    __syncthreads();

    if (tid < B_) {
        const int b = tid;
        int prev = 0, fl = 0;
        for (int c = 0; c < C_; ++c) {
            const int t = tops[b * C_ + c];
            int fin;
            if (c == 0) {
                fin = t;
            } else {
                const float cur = cl[b * C_ + c][t];
                const float pv = cl[b * C_ + c][prev];
                const bool sw = (cur - pv) > TAU_;
                if (sw) fl++;
                fin = sw ? t : prev;
            }
            finals[b * C_ + c] = fin;
            prev = fin;
        }
        flips[b] = fl;
    }
    __syncthreads();

    {
        const int tok = blockIdx.x * 256 + tid;
        const int b = tok >> 12;
        const int c = (tok & (S_ - 1)) >> 7;
        const int e = finals[b * C_ + c];
        float4 v0 = make_float4(e == 0 ? 1.f : 0.f, e == 1 ? 1.f : 0.f,
                                e == 2 ? 1.f : 0.f, e == 3 ? 1.f : 0.f);
        float4 v1 = make_float4(e == 4 ? 1.f : 0.f, e == 5 ? 1.f : 0.f,
                                e == 6 ? 1.f : 0.f, e == 7 ? 1.f : 0.f);
        float4* dst = (float4*)(out + OUT_RW + (size_t)tok * E_);
        dst[0] = v0;
        dst[1] = v1;
    }

    if (blockIdx.x == 0) {
        if (tid < B_ * C_) {
            out[OUT_EI + tid] = (float)finals[tid];
#pragma unroll
            for (int e = 0; e < E_; ++e) out[OUT_CL + tid * E_ + e] = cl[tid][e];
            float m = cl[tid][0];
            for (int e = 1; e < E_; ++e) m = fmaxf(m, cl[tid][e]);
            float pr[E_], s = 0.0f;
            for (int e = 0; e < E_; ++e) { pr[e] = expf(cl[tid][e] - m); s += pr[e]; }
            const float inv = 1.0f / s;
            float h = 0.0f;
            for (int e = 0; e < E_; ++e) { const float pe = pr[e] * inv; h -= pe * logf(pe + 1e-8f); }
            ent[tid] = h;
        }
        __syncthreads();
        if (tid == 0) {
            float esum = 0.0f;
            for (int i = 0; i < B_ * C_; ++i) esum += ent[i];
            out[OUT_GE] = esum / (float)(B_ * C_);

            int cnt[E_];
            for (int e = 0; e < E_; ++e) cnt[e] = 0;
            for (int i = 0; i < B_ * C_; ++i) cnt[finals[i]]++;
            float n2 = 0.0f;
            for (int e = 0; e < E_; ++e) {
                const float u = (float)cnt[e] / (float)(B_ * C_);
                out[OUT_UT + e] = u;
                n2 += u * u;
            }
            const int totfl = flips[0] + flips[1] + flips[2] + flips[3];
            out[OUT_FR] = (float)totfl / (float)(B_ * (C_ - 1));
            out[OUT_RC] = sqrtf(n2);
        }
    }
}

// ---------------------------------------------------------------------------
extern "C" void kernel_launch(void* const* d_in, const int* in_sizes, int n_in,
                              void* d_out, int out_size, void* d_ws, size_t ws_size,
                              hipStream_t stream)
{
    const float* x  = (const float*)d_in[0];
    const float* w1 = (const float*)d_in[2];
    const float* b1 = (const float*)d_in[3];
    const float* w2 = (const float*)d_in[4];
    const float* b2 = (const float*)d_in[5];
    const float* w3 = (const float*)d_in[6];
    const float* b3 = (const float*)d_in[7];
    float* out = (float*)d_out;

    half_t* xh   = (half_t*)d_ws;                    // 64 MB
    half_t* w1t  = xh + (size_t)M_ * D_;             // 4 MB
    half_t* h1h  = w1t + (size_t)H_ * D_;            // 32 MB
    half_t* w2th = h1h + (size_t)M_ * H_;            // 1 MB
    half_t* w2tl = w2th + (size_t)H2_ * H_;          // 1 MB
    float*  cl_acc = (float*)(w2tl + (size_t)H2_ * H_);  // 4 KB

    prep_kernel<<<dim3(10753), dim3(256), 0, stream>>>(x, w1, w2, xh, w1t, w2th, w2tl, cl_acc);
    gemm1_kernel<<<dim3(8, 128), dim3(256), 0, stream>>>(xh, w1t, b1, h1h);
    gemm2_fused_kernel<<<dim3(8, 128), dim3(256), 0, stream>>>(
        h1h, w2th, w2tl, b2, w3, cl_acc);
    final_route_kernel<<<dim3(M_ / 256), dim3(256), 0, stream>>>(cl_acc, b3, out);
}